// Round 8
// baseline (581.364 us; speedup 1.0000x reference)
//
#include <hip/hip_runtime.h>
#include <cstdint>
#include <cstddef>

#define B_   64
#define T_   200
#define NQ_  13523
#define NTOK (B_*T_)   // 12800

// ws layout (float offsets)
#define O_MKT  0          // Mkt[128][64]
#define O_EWT  8192       // eWt[128][128]
#define O_AWT  24576      // aWt[128][128]
#define O_FWT  40960      // fWt[256][128]  (c-major)
#define O_W    73728      // w[NTOK][64]
#define O_EV   892928     // e[NTOK][128]
#define O_AV   2531328    // a[NTOK][128]
#define O_KF   4169728    // kf[NTOK][128]
#define O_PART 5808128    // partial[4][NTOK][128]
// total = 12,361,728 floats = 49.4 MB

#define TOKA 32
#define LSTR 36           // padded LDS row stride (floats); 16B-aligned

typedef float f4v __attribute__((ext_vector_type(4)));

__device__ __forceinline__ float sigmoidf_(float x){ return 1.f/(1.f + __expf(-x)); }

// nontemporal dwordx4 store: builtin needs a clang ext_vector, not HIP float4
__device__ __forceinline__ void nt_store4(const float4& v, float* p){
  f4v t; t.x = v.x; t.y = v.y; t.z = v.z; t.w = v.w;
  __builtin_nontemporal_store(t, (f4v*)p);
}

__global__ __launch_bounds__(256) void k_prep(const float* __restrict__ Mk,
    const float* __restrict__ eW, const float* __restrict__ aW,
    const float* __restrict__ fW, float* __restrict__ ws)
{
  int i = blockIdx.x*256 + threadIdx.x;
  if (i < 8192){  int j = i>>6, m = i&63;  ws[O_MKT+i] = Mk[m*128 + j]; }
  if (i < 16384){ int j = i>>7, d = i&127; ws[O_EWT+i] = eW[d*128 + j];
                                           ws[O_AWT+i] = aW[d*128 + j]; }
  if (i < 32768){ int c = i>>7, d = i&127; ws[O_FWT+i] = fW[d*256 + c]; }
}

// 32 tokens/block. Gathers K,V rows into transposed LDS tiles, then:
//   w = softmax(K @ Mk^T)   (lane = m, 8 items/wave, wave-shuffle softmax)
//   e = sigmoid(V @ eW^T + eb), a = tanh(V @ aW^T + ab), kf = K @ fW[:,128:]^T
__global__ __launch_bounds__(256) void k_embed(const int* __restrict__ q,
    const int* __restrict__ r, const float* __restrict__ kE,
    const float* __restrict__ vE, const float* __restrict__ eb,
    const float* __restrict__ ab, float* __restrict__ ws)
{
  __shared__ float Kt[128*LSTR];   // Kt[j][i] : K transposed
  __shared__ float Vt[128*LSTR];
  __shared__ int qx[2*TOKA];
  const int tid = threadIdx.x;
  const int it0 = blockIdx.x * TOKA;

  if (tid < TOKA){
    int qq = q[it0+tid];
    qx[tid]      = qq;
    qx[TOKA+tid] = qq + NQ_*r[it0+tid];
  }
  __syncthreads();

  {
    const int j  = tid & 127;
    const int wg = tid >> 7;
    #pragma unroll
    for (int rr=0; rr<4; ++rr){
      const int i0 = rr*8 + wg*4;
      float4 kv, vv;
      kv.x = kE[(size_t)qx[i0+0]*128 + j];
      kv.y = kE[(size_t)qx[i0+1]*128 + j];
      kv.z = kE[(size_t)qx[i0+2]*128 + j];
      kv.w = kE[(size_t)qx[i0+3]*128 + j];
      vv.x = vE[(size_t)qx[TOKA+i0+0]*128 + j];
      vv.y = vE[(size_t)qx[TOKA+i0+1]*128 + j];
      vv.z = vE[(size_t)qx[TOKA+i0+2]*128 + j];
      vv.w = vE[(size_t)qx[TOKA+i0+3]*128 + j];
      *(float4*)&Kt[j*LSTR + i0] = kv;
      *(float4*)&Vt[j*LSTR + i0] = vv;
    }
  }
  __syncthreads();

  const int lane = tid & 63;
  const int wv   = tid >> 6;     // wave id: items wv*8 .. wv*8+7

  // ---- logits + softmax -> w  (lane = m) ----
  {
    float acc[8] = {0,0,0,0,0,0,0,0};
    #pragma unroll 4
    for (int j=0;j<128;++j){
      float mk  = ws[O_MKT + j*64 + lane];
      float4 k0 = *(const float4*)&Kt[j*LSTR + wv*8];
      float4 k1 = *(const float4*)&Kt[j*LSTR + wv*8 + 4];
      acc[0] = fmaf(k0.x, mk, acc[0]);
      acc[1] = fmaf(k0.y, mk, acc[1]);
      acc[2] = fmaf(k0.z, mk, acc[2]);
      acc[3] = fmaf(k0.w, mk, acc[3]);
      acc[4] = fmaf(k1.x, mk, acc[4]);
      acc[5] = fmaf(k1.y, mk, acc[5]);
      acc[6] = fmaf(k1.z, mk, acc[6]);
      acc[7] = fmaf(k1.w, mk, acc[7]);
    }
    #pragma unroll
    for (int ii=0;ii<8;++ii){
      float x = acc[ii];
      float mx = x;
      #pragma unroll
      for (int off=32; off>0; off>>=1) mx = fmaxf(mx, __shfl_xor(mx, off));
      float ex = __expf(x - mx);
      float sm = ex;
      #pragma unroll
      for (int off=32; off>0; off>>=1) sm += __shfl_xor(sm, off);
      ws[O_W + (size_t)(it0 + wv*8 + ii)*64 + lane] = ex/sm;
    }
  }

  // ---- e, a, kf  (thread covers d0=lane, d1=lane+64; 8 items) ----
  {
    const int d0 = lane, d1 = lane + 64;
    float aE0[8]={0},aE1[8]={0},aA0[8]={0},aA1[8]={0},aK0[8]={0},aK1[8]={0};
    #pragma unroll 2
    for (int j=0;j<128;++j){
      float we0 = ws[O_EWT + j*128 + d0];
      float we1 = ws[O_EWT + j*128 + d1];
      float wa0 = ws[O_AWT + j*128 + d0];
      float wa1 = ws[O_AWT + j*128 + d1];
      float wf0 = ws[O_FWT + (128+j)*128 + d0];
      float wf1 = ws[O_FWT + (128+j)*128 + d1];
      float4 v0 = *(const float4*)&Vt[j*LSTR + wv*8];
      float4 v1 = *(const float4*)&Vt[j*LSTR + wv*8 + 4];
      float4 k0 = *(const float4*)&Kt[j*LSTR + wv*8];
      float4 k1 = *(const float4*)&Kt[j*LSTR + wv*8 + 4];
      float vv[8] = {v0.x,v0.y,v0.z,v0.w,v1.x,v1.y,v1.z,v1.w};
      float kk[8] = {k0.x,k0.y,k0.z,k0.w,k1.x,k1.y,k1.z,k1.w};
      #pragma unroll
      for (int ii=0;ii<8;++ii){
        aE0[ii] = fmaf(vv[ii], we0, aE0[ii]);
        aE1[ii] = fmaf(vv[ii], we1, aE1[ii]);
        aA0[ii] = fmaf(vv[ii], wa0, aA0[ii]);
        aA1[ii] = fmaf(vv[ii], wa1, aA1[ii]);
        aK0[ii] = fmaf(kk[ii], wf0, aK0[ii]);
        aK1[ii] = fmaf(kk[ii], wf1, aK1[ii]);
      }
    }
    const float eb0 = eb[d0], eb1 = eb[d1];
    const float ab0 = ab[d0], ab1 = ab[d1];
    #pragma unroll
    for (int ii=0;ii<8;++ii){
      size_t it = (size_t)(it0 + wv*8 + ii);
      ws[O_EV + it*128 + d0] = sigmoidf_(aE0[ii] + eb0);
      ws[O_EV + it*128 + d1] = sigmoidf_(aE1[ii] + eb1);
      ws[O_AV + it*128 + d0] = tanhf(aA0[ii] + ab0);
      ws[O_AV + it*128 + d1] = tanhf(aA1[ii] + ab1);
      ws[O_KF + it*128 + d0] = aK0[ii];
      ws[O_KF + it*128 + d1] = aK1[ii];
    }
  }
}

// 512 blocks: (b, m-chunk c of 16, d-half dh of 64). 2 blocks/CU -> 8 waves/CU
// (2 waves/SIMD) so stalls in one block are covered by the other.
//   thread: mgr = tid&15 -> 1 m-row (m = c*16+mgr); dq = tid>>4 -> d0 = dh*64+dq*4
// Cross-m reduction intra-wave: shfl_xor 1/2/4/8 (mgr bits only).
// State = 1 float4/thread; Mv stored nontemporal dwordx4; w/e/a prefetch depth 2.
// No LDS, no barriers in the t-loop.
__global__ __launch_bounds__(256) void k_scan(const float* __restrict__ Mv0,
    float* __restrict__ ws, float* __restrict__ out)
{
  const int tid = threadIdx.x;
  const int bid = blockIdx.x;
  const int b   = bid >> 3;
  const int c   = (bid >> 1) & 3;
  const int dh  = bid & 1;
  const int mgr = tid & 15;        // 16 m-rows, 1 per thread
  const int dq  = tid >> 4;        // 16 d-quads
  const int m   = c*16 + mgr;
  const int d0  = dh*64 + dq*4;

  float* mv = out + NTOK + (size_t)b*201*64*128;

  float4 s = *(const float4*)&Mv0[(size_t)m*128 + d0];
  nt_store4(s, &mv[(size_t)m*128 + d0]);   // t=0 slice

  const float* wp = ws + O_W  + (size_t)b*T_*64  + m;
  const float* ep = ws + O_EV + (size_t)b*T_*128 + d0;
  const float* ap = ws + O_AV + (size_t)b*T_*128 + d0;
  float* pp = ws + O_PART + (size_t)c*NTOK*128 + (size_t)b*T_*128 + d0;

  // depth-2 prefetch ring: A = t, B = t+1, C = t+2 (issued in-loop)
  float  wA = wp[0];
  float4 eA = *(const float4*)(ep);
  float4 aA = *(const float4*)(ap);
  float  wB = wp[64];
  float4 eB = *(const float4*)(ep + 128);
  float4 aB = *(const float4*)(ap + 128);

  for (int t=0; t<T_; ++t){
    const int tn = (t+2 < T_) ? t+2 : T_-1;
    float  wC = wp[(size_t)tn*64];
    float4 eC = *(const float4*)(ep + (size_t)tn*128);
    float4 aC = *(const float4*)(ap + (size_t)tn*128);

    // read partial (pre-update state): r = sum_m w[m]*s[m]  (16 mgr lanes)
    float4 r;
    r.x = wA*s.x; r.y = wA*s.y; r.z = wA*s.z; r.w = wA*s.w;
    #pragma unroll
    for (int off=1; off<16; off<<=1){
      r.x += __shfl_xor(r.x, off);
      r.y += __shfl_xor(r.y, off);
      r.z += __shfl_xor(r.z, off);
      r.w += __shfl_xor(r.w, off);
    }
    if (mgr == 0) *(float4*)&pp[(size_t)t*128] = r;

    // update: s = s + w*(a - e*s)
    float4 u;
    u.x = fmaf(-eA.x, s.x, aA.x);  s.x = fmaf(wA, u.x, s.x);
    u.y = fmaf(-eA.y, s.y, aA.y);  s.y = fmaf(wA, u.y, s.y);
    u.z = fmaf(-eA.z, s.z, aA.z);  s.z = fmaf(wA, u.z, s.z);
    u.w = fmaf(-eA.w, s.w, aA.w);  s.w = fmaf(wA, u.w, s.w);

    nt_store4(s, &mv[(size_t)(t+1)*64*128 + (size_t)m*128 + d0]);

    // rotate prefetch ring
    wA = wB; eA = eB; aA = aB;
    wB = wC; eB = eC; aB = aC;
  }
}

// Sum 4 partials -> read; f = tanh(read @ fW[:,:128]^T + kf + fb); p = sigmoid(f.pW + pb)
__global__ __launch_bounds__(256) void k_out(const float* __restrict__ ws,
    const float* __restrict__ fb, const float* __restrict__ pW,
    const float* __restrict__ pb, float* __restrict__ out)
{
  __shared__ float Rt[128*LSTR];
  const int tid = threadIdx.x;
  const int it0 = blockIdx.x * TOKA;
  {
    const int j  = tid & 127;
    const int wg = tid >> 7;
    const float* P = ws + O_PART;
    #pragma unroll
    for (int rr=0; rr<4; ++rr){
      const int i0 = rr*8 + wg*4;
      float v4[4];
      #pragma unroll
      for (int ii=0;ii<4;++ii){
        size_t base = (size_t)(it0+i0+ii)*128 + j;
        v4[ii] = P[base] + P[(size_t)NTOK*128 + base]
               + P[2*(size_t)NTOK*128 + base] + P[3*(size_t)NTOK*128 + base];
      }
      *(float4*)&Rt[j*LSTR + i0] = make_float4(v4[0],v4[1],v4[2],v4[3]);
    }
  }
  __syncthreads();
  const int lane = tid & 63, wv = tid >> 6;
  const int d0 = lane, d1 = lane + 64;
  float a0[8]={0,0,0,0,0,0,0,0}, a1[8]={0,0,0,0,0,0,0,0};
  #pragma unroll 2
  for (int j=0;j<128;++j){
    float w0 = ws[O_FWT + j*128 + d0];
    float w1 = ws[O_FWT + j*128 + d1];
    float4 r0 = *(const float4*)&Rt[j*LSTR + wv*8];
    float4 r1 = *(const float4*)&Rt[j*LSTR + wv*8 + 4];
    float rv[8] = {r0.x,r0.y,r0.z,r0.w,r1.x,r1.y,r1.z,r1.w};
    #pragma unroll
    for (int ii=0;ii<8;++ii){
      a0[ii] = fmaf(rv[ii], w0, a0[ii]);
      a1[ii] = fmaf(rv[ii], w1, a1[ii]);
    }
  }
  const float fb0 = fb[d0], fb1 = fb[d1];
  const float pw0 = pW[d0], pw1 = pW[d1];
  #pragma unroll
  for (int ii=0;ii<8;++ii){
    size_t it = (size_t)(it0 + wv*8 + ii);
    float f0 = tanhf(a0[ii] + ws[O_KF + it*128 + d0] + fb0);
    float f1 = tanhf(a1[ii] + ws[O_KF + it*128 + d1] + fb1);
    float part = fmaf(f0, pw0, f1*pw1);
    #pragma unroll
    for (int off=32; off>0; off>>=1) part += __shfl_xor(part, off);
    if (lane == 0) out[it] = sigmoidf_(part + pb[0]);
  }
}

extern "C" void kernel_launch(void* const* d_in, const int* in_sizes, int n_in,
                              void* d_out, int out_size, void* d_ws, size_t ws_size,
                              hipStream_t stream)
{
  const int*   q   = (const int*)d_in[0];
  const int*   r   = (const int*)d_in[1];
  const float* kE  = (const float*)d_in[2];
  const float* vE  = (const float*)d_in[3];
  const float* Mk  = (const float*)d_in[4];
  const float* Mv0 = (const float*)d_in[5];
  const float* fW  = (const float*)d_in[6];
  const float* fb  = (const float*)d_in[7];
  const float* pW  = (const float*)d_in[8];
  const float* pb  = (const float*)d_in[9];
  const float* eW  = (const float*)d_in[10];
  const float* eb  = (const float*)d_in[11];
  const float* aW  = (const float*)d_in[12];
  const float* ab  = (const float*)d_in[13];
  float* out = (float*)d_out;
  float* ws  = (float*)d_ws;

  k_prep <<<128, 256, 0, stream>>>(Mk, eW, aW, fW, ws);
  k_embed<<<NTOK/TOKA, 256, 0, stream>>>(q, r, kE, vE, eb, ab, ws);
  k_scan <<<512, 256, 0, stream>>>(Mv0, ws, out);
  k_out  <<<NTOK/TOKA, 256, 0, stream>>>(ws, fb, pW, pb, out);
}

// Round 9
// 528.042 us; speedup vs baseline: 1.1010x; 1.1010x over previous
//
#include <hip/hip_runtime.h>
#include <cstdint>
#include <cstddef>

#define B_   64
#define T_   200
#define NQ_  13523
#define NTOK (B_*T_)   // 12800

// ws layout (float offsets)
#define O_MKT  0          // Mkt[128][64]
#define O_EWT  8192       // eWt[128][128]
#define O_AWT  24576      // aWt[128][128]
#define O_FWT  40960      // fWt[256][128]  (c-major)
#define O_W    73728      // w[NTOK][64]
#define O_EV   892928     // e[NTOK][128]
#define O_AV   2531328    // a[NTOK][128]
#define O_KF   4169728    // kf[NTOK][128]
#define O_PART 5808128    // partial[4][NTOK][128]
// total = 12,361,728 floats = 49.4 MB

#define TOKA 32
#define LSTR 36           // padded LDS row stride (floats); 16B-aligned

typedef float f4v __attribute__((ext_vector_type(4)));

// fast sigmoid/tanh: __expf + v_rcp-based divide (~1e-6 abs err, tol is 3.9e-3)
__device__ __forceinline__ float sigmoidf_(float x){
  return __fdividef(1.f, 1.f + __expf(-x));
}
__device__ __forceinline__ float tanhf_(float x){
  float ax = fabsf(x);
  float e  = __expf(-2.f*ax);
  float t  = __fdividef(1.f - e, 1.f + e);
  return copysignf(t, x);
}

// nontemporal dwordx4 store: builtin needs a clang ext_vector, not HIP float4
__device__ __forceinline__ void nt_store4(const float4& v, float* p){
  f4v t; t.x = v.x; t.y = v.y; t.z = v.z; t.w = v.w;
  __builtin_nontemporal_store(t, (f4v*)p);
}

__global__ __launch_bounds__(256) void k_prep(const float* __restrict__ Mk,
    const float* __restrict__ eW, const float* __restrict__ aW,
    const float* __restrict__ fW, float* __restrict__ ws)
{
  int i = blockIdx.x*256 + threadIdx.x;
  if (i < 8192){  int j = i>>6, m = i&63;  ws[O_MKT+i] = Mk[m*128 + j]; }
  if (i < 16384){ int j = i>>7, d = i&127; ws[O_EWT+i] = eW[d*128 + j];
                                           ws[O_AWT+i] = aW[d*128 + j]; }
  if (i < 32768){ int c = i>>7, d = i&127; ws[O_FWT+i] = fW[d*256 + c]; }
}

// 32 tokens/block. Gathers K,V rows into transposed LDS tiles, then:
//   w = softmax(K @ Mk^T)   (lane = m, 8 items/wave, wave-shuffle softmax)
//   e = sigmoid(V @ eW^T + eb), a = tanh(V @ aW^T + ab), kf = K @ fW[:,128:]^T
__global__ __launch_bounds__(256) void k_embed(const int* __restrict__ q,
    const int* __restrict__ r, const float* __restrict__ kE,
    const float* __restrict__ vE, const float* __restrict__ eb,
    const float* __restrict__ ab, float* __restrict__ ws)
{
  __shared__ float Kt[128*LSTR];   // Kt[j][i] : K transposed
  __shared__ float Vt[128*LSTR];
  __shared__ int qx[2*TOKA];
  const int tid = threadIdx.x;
  const int it0 = blockIdx.x * TOKA;

  if (tid < TOKA){
    int qq = q[it0+tid];
    qx[tid]      = qq;
    qx[TOKA+tid] = qq + NQ_*r[it0+tid];
  }
  __syncthreads();

  {
    const int j  = tid & 127;
    const int wg = tid >> 7;
    #pragma unroll
    for (int rr=0; rr<4; ++rr){
      const int i0 = rr*8 + wg*4;
      float4 kv, vv;
      kv.x = kE[(size_t)qx[i0+0]*128 + j];
      kv.y = kE[(size_t)qx[i0+1]*128 + j];
      kv.z = kE[(size_t)qx[i0+2]*128 + j];
      kv.w = kE[(size_t)qx[i0+3]*128 + j];
      vv.x = vE[(size_t)qx[TOKA+i0+0]*128 + j];
      vv.y = vE[(size_t)qx[TOKA+i0+1]*128 + j];
      vv.z = vE[(size_t)qx[TOKA+i0+2]*128 + j];
      vv.w = vE[(size_t)qx[TOKA+i0+3]*128 + j];
      *(float4*)&Kt[j*LSTR + i0] = kv;
      *(float4*)&Vt[j*LSTR + i0] = vv;
    }
  }
  __syncthreads();

  const int lane = tid & 63;
  const int wv   = tid >> 6;     // wave id: items wv*8 .. wv*8+7

  // ---- logits + softmax -> w  (lane = m) ----
  {
    float acc[8] = {0,0,0,0,0,0,0,0};
    #pragma unroll 4
    for (int j=0;j<128;++j){
      float mk  = ws[O_MKT + j*64 + lane];
      float4 k0 = *(const float4*)&Kt[j*LSTR + wv*8];
      float4 k1 = *(const float4*)&Kt[j*LSTR + wv*8 + 4];
      acc[0] = fmaf(k0.x, mk, acc[0]);
      acc[1] = fmaf(k0.y, mk, acc[1]);
      acc[2] = fmaf(k0.z, mk, acc[2]);
      acc[3] = fmaf(k0.w, mk, acc[3]);
      acc[4] = fmaf(k1.x, mk, acc[4]);
      acc[5] = fmaf(k1.y, mk, acc[5]);
      acc[6] = fmaf(k1.z, mk, acc[6]);
      acc[7] = fmaf(k1.w, mk, acc[7]);
    }
    #pragma unroll
    for (int ii=0;ii<8;++ii){
      float x = acc[ii];
      float mx = x;
      #pragma unroll
      for (int off=32; off>0; off>>=1) mx = fmaxf(mx, __shfl_xor(mx, off));
      float ex = __expf(x - mx);
      float sm = ex;
      #pragma unroll
      for (int off=32; off>0; off>>=1) sm += __shfl_xor(sm, off);
      ws[O_W + (size_t)(it0 + wv*8 + ii)*64 + lane] = __fdividef(ex, sm);
    }
  }

  // ---- e, a, kf  (thread covers d0=lane, d1=lane+64; 8 items) ----
  {
    const int d0 = lane, d1 = lane + 64;
    float aE0[8]={0},aE1[8]={0},aA0[8]={0},aA1[8]={0},aK0[8]={0},aK1[8]={0};
    #pragma unroll 2
    for (int j=0;j<128;++j){
      float we0 = ws[O_EWT + j*128 + d0];
      float we1 = ws[O_EWT + j*128 + d1];
      float wa0 = ws[O_AWT + j*128 + d0];
      float wa1 = ws[O_AWT + j*128 + d1];
      float wf0 = ws[O_FWT + (128+j)*128 + d0];
      float wf1 = ws[O_FWT + (128+j)*128 + d1];
      float4 v0 = *(const float4*)&Vt[j*LSTR + wv*8];
      float4 v1 = *(const float4*)&Vt[j*LSTR + wv*8 + 4];
      float4 k0 = *(const float4*)&Kt[j*LSTR + wv*8];
      float4 k1 = *(const float4*)&Kt[j*LSTR + wv*8 + 4];
      float vv[8] = {v0.x,v0.y,v0.z,v0.w,v1.x,v1.y,v1.z,v1.w};
      float kk[8] = {k0.x,k0.y,k0.z,k0.w,k1.x,k1.y,k1.z,k1.w};
      #pragma unroll
      for (int ii=0;ii<8;++ii){
        aE0[ii] = fmaf(vv[ii], we0, aE0[ii]);
        aE1[ii] = fmaf(vv[ii], we1, aE1[ii]);
        aA0[ii] = fmaf(vv[ii], wa0, aA0[ii]);
        aA1[ii] = fmaf(vv[ii], wa1, aA1[ii]);
        aK0[ii] = fmaf(kk[ii], wf0, aK0[ii]);
        aK1[ii] = fmaf(kk[ii], wf1, aK1[ii]);
      }
    }
    const float eb0 = eb[d0], eb1 = eb[d1];
    const float ab0 = ab[d0], ab1 = ab[d1];
    #pragma unroll
    for (int ii=0;ii<8;++ii){
      size_t it = (size_t)(it0 + wv*8 + ii);
      ws[O_EV + it*128 + d0] = sigmoidf_(aE0[ii] + eb0);
      ws[O_EV + it*128 + d1] = sigmoidf_(aE1[ii] + eb1);
      ws[O_AV + it*128 + d0] = tanhf_(aA0[ii] + ab0);
      ws[O_AV + it*128 + d1] = tanhf_(aA1[ii] + ab1);
      ws[O_KF + it*128 + d0] = aK0[ii];
      ws[O_KF + it*128 + d1] = aK1[ii];
    }
  }
}

// One block per (b, m-chunk of 16). BARRIER-FREE scan (proven R5 mapping):
//   thread = (mgr = tid&7  -> 2 m-rows: m0=c*16+mgr*2, m0+1;
//             dq  = tid>>3 -> d0 = dq*4)
// Per wave, each m-row's stores cover 8 lanes x 16B = 128B contiguous segments.
// Cross-m read-reduction intra-wave (shfl_xor 1/2/4 flips mgr bits only).
// State in registers (2x float4); Mv stored nontemporal dwordx4;
// w/e/a prefetched 2 steps ahead. No LDS, no __syncthreads in the loop.
__global__ __launch_bounds__(256) void k_scan(const float* __restrict__ Mv0,
    float* __restrict__ ws, float* __restrict__ out)
{
  const int tid = threadIdx.x;
  const int b   = blockIdx.x >> 2;
  const int c   = blockIdx.x & 3;
  const int mgr = tid & 7;         // 8 groups x 2 m-rows
  const int dq  = tid >> 3;        // 32 d-quads
  const int m0  = c*16 + mgr*2;
  const int d0  = dq*4;

  float* mv = out + NTOK + (size_t)b*201*64*128;

  float4 s0 = *(const float4*)&Mv0[(size_t)(m0+0)*128 + d0];
  float4 s1 = *(const float4*)&Mv0[(size_t)(m0+1)*128 + d0];
  nt_store4(s0, &mv[(size_t)(m0+0)*128 + d0]); // t=0 slice
  nt_store4(s1, &mv[(size_t)(m0+1)*128 + d0]);

  const float* wp = ws + O_W  + (size_t)b*T_*64  + m0;
  const float* ep = ws + O_EV + (size_t)b*T_*128 + d0;
  const float* ap = ws + O_AV + (size_t)b*T_*128 + d0;
  float* pp = ws + O_PART + (size_t)c*NTOK*128 + (size_t)b*T_*128 + d0;

  // depth-2 prefetch: A = t, B = t+1, C = t+2 (issued in-loop)
  float2 wA = *(const float2*)(wp);
  float4 eA = *(const float4*)(ep);
  float4 aA = *(const float4*)(ap);
  float2 wB = *(const float2*)(wp + 64);
  float4 eB = *(const float4*)(ep + 128);
  float4 aB = *(const float4*)(ap + 128);

  for (int t=0; t<T_; ++t){
    const int tn = (t+2 < T_) ? t+2 : T_-1;
    float2 wC = *(const float2*)(wp + (size_t)tn*64);
    float4 eC = *(const float4*)(ep + (size_t)tn*128);
    float4 aC = *(const float4*)(ap + (size_t)tn*128);

    // read partial (uses pre-update state): r[i] = wA.x*s0[i] + wA.y*s1[i]
    float4 r;
    r.x = fmaf(wA.x, s0.x, wA.y*s1.x);
    r.y = fmaf(wA.x, s0.y, wA.y*s1.y);
    r.z = fmaf(wA.x, s0.z, wA.y*s1.z);
    r.w = fmaf(wA.x, s0.w, wA.y*s1.w);
    #pragma unroll
    for (int off=1; off<8; off<<=1){
      r.x += __shfl_xor(r.x, off);
      r.y += __shfl_xor(r.y, off);
      r.z += __shfl_xor(r.z, off);
      r.w += __shfl_xor(r.w, off);
    }
    if (mgr == 0) *(float4*)&pp[(size_t)t*128] = r;

    // update: s = s + w*(a - e*s)
    float4 u0, u1;
    u0.x = fmaf(-eA.x, s0.x, aA.x);  s0.x = fmaf(wA.x, u0.x, s0.x);
    u0.y = fmaf(-eA.y, s0.y, aA.y);  s0.y = fmaf(wA.x, u0.y, s0.y);
    u0.z = fmaf(-eA.z, s0.z, aA.z);  s0.z = fmaf(wA.x, u0.z, s0.z);
    u0.w = fmaf(-eA.w, s0.w, aA.w);  s0.w = fmaf(wA.x, u0.w, s0.w);
    u1.x = fmaf(-eA.x, s1.x, aA.x);  s1.x = fmaf(wA.y, u1.x, s1.x);
    u1.y = fmaf(-eA.y, s1.y, aA.y);  s1.y = fmaf(wA.y, u1.y, s1.y);
    u1.z = fmaf(-eA.z, s1.z, aA.z);  s1.z = fmaf(wA.y, u1.z, s1.z);
    u1.w = fmaf(-eA.w, s1.w, aA.w);  s1.w = fmaf(wA.y, u1.w, s1.w);

    float* mvt = mv + (size_t)(t+1)*64*128;
    nt_store4(s0, &mvt[(size_t)(m0+0)*128 + d0]);
    nt_store4(s1, &mvt[(size_t)(m0+1)*128 + d0]);

    // rotate prefetch ring
    wA = wB; eA = eB; aA = aB;
    wB = wC; eB = eC; aB = aC;
  }
}

// Sum 4 partials -> read; f = tanh(read @ fW[:,:128]^T + kf + fb); p = sigmoid(f.pW + pb)
__global__ __launch_bounds__(256) void k_out(const float* __restrict__ ws,
    const float* __restrict__ fb, const float* __restrict__ pW,
    const float* __restrict__ pb, float* __restrict__ out)
{
  __shared__ float Rt[128*LSTR];
  const int tid = threadIdx.x;
  const int it0 = blockIdx.x * TOKA;
  {
    const int j  = tid & 127;
    const int wg = tid >> 7;
    const float* P = ws + O_PART;
    #pragma unroll
    for (int rr=0; rr<4; ++rr){
      const int i0 = rr*8 + wg*4;
      float v4[4];
      #pragma unroll
      for (int ii=0;ii<4;++ii){
        size_t base = (size_t)(it0+i0+ii)*128 + j;
        v4[ii] = P[base] + P[(size_t)NTOK*128 + base]
               + P[2*(size_t)NTOK*128 + base] + P[3*(size_t)NTOK*128 + base];
      }
      *(float4*)&Rt[j*LSTR + i0] = make_float4(v4[0],v4[1],v4[2],v4[3]);
    }
  }
  __syncthreads();
  const int lane = tid & 63, wv = tid >> 6;
  const int d0 = lane, d1 = lane + 64;
  float a0[8]={0,0,0,0,0,0,0,0}, a1[8]={0,0,0,0,0,0,0,0};
  #pragma unroll 2
  for (int j=0;j<128;++j){
    float w0 = ws[O_FWT + j*128 + d0];
    float w1 = ws[O_FWT + j*128 + d1];
    float4 r0 = *(const float4*)&Rt[j*LSTR + wv*8];
    float4 r1 = *(const float4*)&Rt[j*LSTR + wv*8 + 4];
    float rv[8] = {r0.x,r0.y,r0.z,r0.w,r1.x,r1.y,r1.z,r1.w};
    #pragma unroll
    for (int ii=0;ii<8;++ii){
      a0[ii] = fmaf(rv[ii], w0, a0[ii]);
      a1[ii] = fmaf(rv[ii], w1, a1[ii]);
    }
  }
  const float fb0 = fb[d0], fb1 = fb[d1];
  const float pw0 = pW[d0], pw1 = pW[d1];
  #pragma unroll
  for (int ii=0;ii<8;++ii){
    size_t it = (size_t)(it0 + wv*8 + ii);
    float f0 = tanhf_(a0[ii] + ws[O_KF + it*128 + d0] + fb0);
    float f1 = tanhf_(a1[ii] + ws[O_KF + it*128 + d1] + fb1);
    float part = fmaf(f0, pw0, f1*pw1);
    #pragma unroll
    for (int off=32; off>0; off>>=1) part += __shfl_xor(part, off);
    if (lane == 0) out[it] = sigmoidf_(part + pb[0]);
  }
}

extern "C" void kernel_launch(void* const* d_in, const int* in_sizes, int n_in,
                              void* d_out, int out_size, void* d_ws, size_t ws_size,
                              hipStream_t stream)
{
  const int*   q   = (const int*)d_in[0];
  const int*   r   = (const int*)d_in[1];
  const float* kE  = (const float*)d_in[2];
  const float* vE  = (const float*)d_in[3];
  const float* Mk  = (const float*)d_in[4];
  const float* Mv0 = (const float*)d_in[5];
  const float* fW  = (const float*)d_in[6];
  const float* fb  = (const float*)d_in[7];
  const float* pW  = (const float*)d_in[8];
  const float* pb  = (const float*)d_in[9];
  const float* eW  = (const float*)d_in[10];
  const float* eb  = (const float*)d_in[11];
  const float* aW  = (const float*)d_in[12];
  const float* ab  = (const float*)d_in[13];
  float* out = (float*)d_out;
  float* ws  = (float*)d_ws;

  k_prep <<<128, 256, 0, stream>>>(Mk, eW, aW, fW, ws);
  k_embed<<<NTOK/TOKA, 256, 0, stream>>>(q, r, kE, vE, eb, ab, ws);
  k_scan <<<256, 256, 0, stream>>>(Mv0, ws, out);
  k_out  <<<NTOK/TOKA, 256, 0, stream>>>(ws, fb, pW, pb, out);
}